// Round 1
// baseline (1027.609 us; speedup 1.0000x reference)
//
#include <hip/hip_runtime.h>

typedef _Float16 f16;
typedef __attribute__((ext_vector_type(8))) _Float16 half8;   // MFMA A/B frag (4 VGPRs)
typedef __attribute__((ext_vector_type(4))) _Float16 half4;
typedef __attribute__((ext_vector_type(4))) float   f4;       // MFMA C/D

#define NTOK   196
#define MROWS  50176            // 256 * 196
#define HIDN   1536
#define HPC    192              // per-head channels in h (q32|k32|v128)
#define DHD    1024             // H * 128
#define EPSV   1e-5f
#define SCALEV 0.17677669529663687f

// async global->LDS, 16B per lane; LDS dest is wave-uniform base + lane*16
#define GLD16(gp, lp) __builtin_amdgcn_global_load_lds( \
    (const __attribute__((address_space(1))) unsigned int*)(gp), \
    (__attribute__((address_space(3))) unsigned int*)(lp), 16, 0, 0)

// rotation swizzle: spreads banks for reads (row bits 0-3) AND writes (row bits 3-5)
__device__ inline int swz8(int row) { return (((row & 7) ^ ((row >> 3) & 7))) * 8; }

// ---------------- f32 -> f16 convert (vectorized)
__global__ void cvt_f32_f16(const float* __restrict__ src, f16* __restrict__ dst, int n4)
{
    int i = blockIdx.x * blockDim.x + threadIdx.x;
    if (i < n4) {
        float4 v = *(const float4*)&src[i * 4];
        half4 h = { (f16)v.x, (f16)v.y, (f16)v.z, (f16)v.w };
        *(half4*)&dst[i * 4] = h;
    }
}

// ---------------- bias_full[h][208][224] f16: idxs gather resolved once; pad = -30000 (mask baked in)
__global__ void build_bias(const float* __restrict__ bt, const int* __restrict__ idxs,
                           f16* __restrict__ bf)
{
    int i = blockIdx.x * 256 + threadIdx.x;
    if (i >= 8 * 208 * 224) return;
    int k = i % 224, q = (i / 224) % 208, h = i / (224 * 208);
    float v = -30000.f;
    if (q < NTOK && k < NTOK) v = bt[h * NTOK + idxs[q * NTOK + k]];
    bf[i] = (f16)v;
}

// ---------------- GEMM1: h = x @ Wqkv^T  (f16 in, f16 out + BN stats), global_load_lds staging
__global__ __launch_bounds__(256) void gemm1_qkv(
    const f16* __restrict__ A, const f16* __restrict__ B,
    f16* __restrict__ C, float* __restrict__ gsum, float* __restrict__ gsq)
{
    const int K = 256, ldc = HIDN;
    __shared__ f16 As[128 * 32];      // unpadded: required by global_load_lds layout
    __shared__ f16 Bs[128 * 32];
    __shared__ float ssum[128], ssq[128];

    const int t = threadIdx.x;
    const int m0 = blockIdx.x * 128, n0 = blockIdx.y * 128;
    const int wid = t >> 6, lane = t & 63, quad = lane >> 4, lm = lane & 15;
    const int wm = (wid >> 1) * 64, wn = (wid & 1) * 64;

    // staging geometry: wave w slot s covers rows w*32+s*16 .. +15 (lane r>>2), col8 = (lane&3)*8
    const int lr = lane >> 2, lc = (lane & 3) * 8;
    f16* As0 = &As[(wid * 2 + 0) * 512];
    f16* As1 = &As[(wid * 2 + 1) * 512];
    f16* Bs0 = &Bs[(wid * 2 + 0) * 512];
    f16* Bs1 = &Bs[(wid * 2 + 1) * 512];
    const f16* Ab = A + (long)(m0 + wid * 32 + lr) * K + lc;
    const f16* Bb = B + (long)(n0 + wid * 32 + lr) * K + lc;

    f4 acc[4][4] = {};

    for (int k0 = 0; k0 < K; k0 += 32) {
        GLD16(Ab + k0,          As0);
        GLD16(Ab + 16 * K + k0, As1);
        GLD16(Bb + k0,          Bs0);
        GLD16(Bb + 16 * K + k0, Bs1);
        __syncthreads();
        half8 a[4], b[4];
        #pragma unroll
        for (int i = 0; i < 4; ++i) a[i] = *(const half8*)&As[(wm + i*16 + lm) * 32 + quad * 8];
        #pragma unroll
        for (int j = 0; j < 4; ++j) b[j] = *(const half8*)&Bs[(wn + j*16 + lm) * 32 + quad * 8];
        #pragma unroll
        for (int i = 0; i < 4; ++i)
            #pragma unroll
            for (int j = 0; j < 4; ++j)
                acc[i][j] = __builtin_amdgcn_mfma_f32_16x16x32_f16(a[i], b[j], acc[i][j], 0, 0, 0);
        __syncthreads();
    }

    if (t < 128) { ssum[t] = 0.f; ssq[t] = 0.f; }
    __syncthreads();

    #pragma unroll
    for (int j = 0; j < 4; ++j) {
        int nl = wn + j*16 + lm;
        float psum = 0.f, psq = 0.f;
        #pragma unroll
        for (int i = 0; i < 4; ++i) {
            #pragma unroll
            for (int r = 0; r < 4; ++r) {
                int ml = wm + i*16 + quad*4 + r;
                float v = acc[i][j][r];
                f16 uh = (f16)v;
                float vb = (float)uh;
                C[(long)(m0 + ml) * ldc + n0 + nl] = uh;
                psum += vb; psq += vb * vb;
            }
        }
        atomicAdd(&ssum[nl], psum);
        atomicAdd(&ssq[nl], psq);
    }
    __syncthreads();
    if (t < 128) {
        atomicAdd(&gsum[n0 + t], ssum[t]);
        atomicAdd(&gsq[n0 + t],  ssq[t]);
    }
}

// ---------------- GEMM2: p = o @ Wproj^T  (f16 in, f32 out + BN stats), global_load_lds staging
__global__ __launch_bounds__(256) void gemm2_proj(
    const f16* __restrict__ A, const f16* __restrict__ B,
    float* __restrict__ C, float* __restrict__ gsum, float* __restrict__ gsq)
{
    const int K = 1024, ldc = 256;
    __shared__ f16 As[128 * 32];
    __shared__ f16 Bs[128 * 32];
    __shared__ float ssum[128], ssq[128];

    const int t = threadIdx.x;
    const int m0 = blockIdx.x * 128, n0 = blockIdx.y * 128;
    const int wid = t >> 6, lane = t & 63, quad = lane >> 4, lm = lane & 15;
    const int wm = (wid >> 1) * 64, wn = (wid & 1) * 64;

    const int lr = lane >> 2, lc = (lane & 3) * 8;
    f16* As0 = &As[(wid * 2 + 0) * 512];
    f16* As1 = &As[(wid * 2 + 1) * 512];
    f16* Bs0 = &Bs[(wid * 2 + 0) * 512];
    f16* Bs1 = &Bs[(wid * 2 + 1) * 512];
    const f16* Ab = A + (long)(m0 + wid * 32 + lr) * K + lc;
    const f16* Bb = B + (long)(n0 + wid * 32 + lr) * K + lc;

    f4 acc[4][4] = {};

    for (int k0 = 0; k0 < K; k0 += 32) {
        GLD16(Ab + k0,          As0);
        GLD16(Ab + 16 * K + k0, As1);
        GLD16(Bb + k0,          Bs0);
        GLD16(Bb + 16 * K + k0, Bs1);
        __syncthreads();
        half8 a[4], b[4];
        #pragma unroll
        for (int i = 0; i < 4; ++i) a[i] = *(const half8*)&As[(wm + i*16 + lm) * 32 + quad * 8];
        #pragma unroll
        for (int j = 0; j < 4; ++j) b[j] = *(const half8*)&Bs[(wn + j*16 + lm) * 32 + quad * 8];
        #pragma unroll
        for (int i = 0; i < 4; ++i)
            #pragma unroll
            for (int j = 0; j < 4; ++j)
                acc[i][j] = __builtin_amdgcn_mfma_f32_16x16x32_f16(a[i], b[j], acc[i][j], 0, 0, 0);
        __syncthreads();
    }

    if (t < 128) { ssum[t] = 0.f; ssq[t] = 0.f; }
    __syncthreads();

    #pragma unroll
    for (int j = 0; j < 4; ++j) {
        int nl = wn + j*16 + lm;
        float psum = 0.f, psq = 0.f;
        #pragma unroll
        for (int i = 0; i < 4; ++i) {
            #pragma unroll
            for (int r = 0; r < 4; ++r) {
                int ml = wm + i*16 + quad*4 + r;
                float v = acc[i][j][r];
                C[(long)(m0 + ml) * ldc + n0 + nl] = v;
                psum += v; psq += v * v;
            }
        }
        atomicAdd(&ssum[nl], psum);
        atomicAdd(&ssq[nl], psq);
    }
    __syncthreads();
    if (t < 128) {
        atomicAdd(&gsum[n0 + t], ssum[t]);
        atomicAdd(&gsq[n0 + t],  ssq[t]);
    }
}

__global__ void bn_fin(const float* __restrict__ gsum, const float* __restrict__ gsq,
                       const float* __restrict__ g, const float* __restrict__ b,
                       float* __restrict__ a_out, float* __restrict__ s_out, int nch)
{
    int c = blockIdx.x * blockDim.x + threadIdx.x;
    if (c >= nch) return;
    float inv  = 1.f / (float)MROWS;
    float mean = gsum[c] * inv;
    float var  = gsq[c] * inv - mean * mean;
    float a    = g[c] * rsqrtf(var + EPSV);
    a_out[c] = a;
    s_out[c] = b[c] - mean * a;
}

// ---------------- attention: one block (8 waves) per (batch, head).
// v2: swapped QK^T (S^T = K·Q^T) puts q in lm, k within lane -> softmax = 2 shuffles;
// PV via mfma_16x16x16 consumes P directly from registers (no ps LDS roundtrip);
// q fragment loaded per-wave from global (no qs LDS). LDS = 80,384 B -> 2 blocks/CU.
__global__ __launch_bounds__(512, 4) void attn_kernel(
    const f16* __restrict__ hbuf, const float* __restrict__ a1, const float* __restrict__ s1,
    const f16* __restrict__ bf, f16* __restrict__ obuf)
{
    __shared__ f16   ks[208][32];
    __shared__ f16   vT[128][256];
    __shared__ float af[192], sf[192];

    const int t  = threadIdx.x;
    const int bb = blockIdx.x >> 3;
    const int hh = blockIdx.x & 7;
    const int wid = t >> 6, lane = t & 63, quad = lane >> 4, lm = lane & 15;

    if (t < 192) { af[t] = a1[hh * HPC + t]; sf[t] = s1[hh * HPC + t]; }
    half8 z8 = {};
    for (int i = t; i < 4096; i += 512) *(half8*)&vT[i >> 5][(i & 31) * 8] = z8;
    for (int i = t; i < 12 * 32; i += 512) ks[196 + (i >> 5)][i & 31] = (f16)0.f;
    __syncthreads();

    // stage k/v (channels 32..191) with BN1 affine, rotation-swizzled placement
    {
        int t8 = t & 7;
        for (int rr = t >> 3; rr < NTOK; rr += 64) {
            const f16* hrow = hbuf + (long)(bb * NTOK + rr) * HIDN + hh * HPC;
            int sr = swz8(rr);
            #pragma unroll
            for (int cc = 0; cc < 3; ++cc) {
                int cb = 32 + (t8 + cc * 8) * 8;   // 32..216 step 8; skip >=192
                if (cb >= 192) continue;
                half8 raw = *(const half8*)(hrow + cb);
                f16 ov[8];
                #pragma unroll
                for (int e = 0; e < 8; ++e)
                    ov[e] = (f16)((float)raw[e] * af[cb + e] + sf[cb + e]);
                if (cb < 64) {
                    #pragma unroll
                    for (int e = 0; e < 8; ++e) ks[rr][(cb - 32 + e + sr) & 31] = ov[e];
                } else {
                    #pragma unroll
                    for (int e = 0; e < 8; ++e) {
                        int c = cb - 64 + e;
                        vT[c][(rr + swz8(c)) & 255] = ov[e];
                    }
                }
            }
        }
    }
    __syncthreads();

    const int nmt = (wid + 8 < 13) ? 2 : 1;
    const f16* bfh = bf + hh * 208 * 224;

    for (int pass = 0; pass < nmt; ++pass) {
        const int mt = wid + pass * 8;
        const int qrow = mt * 16 + lm;                       // 0..207 (>=196 masked rows)

        // ---- q B-frag direct from global + BN1 affine (q = channels 0..31)
        long grow = (long)bb * NTOK + qrow;
        if (grow > (long)(MROWS - 1)) grow = MROWS - 1;      // clamp tail OOB (values masked)
        half8 qraw = *(const half8*)(hbuf + grow * HIDN + hh * HPC + quad * 8);
        half8 qf;
        #pragma unroll
        for (int e = 0; e < 8; ++e)
            qf[e] = (f16)((float)qraw[e] * af[quad * 8 + e] + sf[quad * 8 + e]);

        // ---- S^T = K·Q^T (13 MFMAs). Lane holds q = qrow (col=lm), k = nt*16 + quad*4 + r.
        f4 sreg[13];
        #pragma unroll
        for (int nt = 0; nt < 13; ++nt) {
            int krow = nt * 16 + lm;
            half8 ak = *(const half8*)&ks[krow][(quad * 8 + swz8(krow)) & 31];
            f4 z = {};
            sreg[nt] = __builtin_amdgcn_mfma_f32_16x16x32_f16(ak, qf, z, 0, 0, 0);
        }

        // ---- scale + bias (mask baked into bias pad rows/cols), running max
        const f16* brow = bfh + qrow * 224 + quad * 4;
        float m = -3.0e38f;
        #pragma unroll
        for (int nt = 0; nt < 13; ++nt) {
            half4 b4 = *(const half4*)(brow + nt * 16);
            #pragma unroll
            for (int r = 0; r < 4; ++r) {
                sreg[nt][r] = sreg[nt][r] * SCALEV + (float)b4[r];
                m = fmaxf(m, sreg[nt][r]);
            }
        }
        m = fmaxf(m, __shfl_xor(m, 16));
        m = fmaxf(m, __shfl_xor(m, 32));

        // ---- exp + sum; P stays unnormalized (<=1) in registers as PV A-frags
        float s = 0.f;
        half4 ap[13];
        #pragma unroll
        for (int nt = 0; nt < 13; ++nt) {
            float e0 = __expf(sreg[nt][0] - m);
            float e1 = __expf(sreg[nt][1] - m);
            float e2 = __expf(sreg[nt][2] - m);
            float e3 = __expf(sreg[nt][3] - m);
            s += (e0 + e1) + (e2 + e3);
            ap[nt] = half4{ (f16)e0, (f16)e1, (f16)e2, (f16)e3 };
        }
        s += __shfl_xor(s, 16);
        s += __shfl_xor(s, 32);
        float rinv = 1.f / s;

        // redistribute rinv to output layout (row = quad*4+r)
        float rv[4];
        #pragma unroll
        for (int r = 0; r < 4; ++r) rv[r] = __shfl(rinv, quad * 4 + r);

        // ---- O = P·V via 16x16x16 (A-frag = ap, matches register layout exactly)
        #pragma unroll
        for (int ct = 0; ct < 8; ++ct) {
            int c = ct * 16 + lm;
            int sc = swz8(c);
            f4 oa = {};
            #pragma unroll
            for (int nt = 0; nt < 13; ++nt) {
                half4 bv = *(const half4*)&vT[c][(nt * 16 + quad * 4 + sc) & 255];
                oa = __builtin_amdgcn_mfma_f32_16x16x16f16(ap[nt], bv, oa, 0, 0, 0);
            }
            #pragma unroll
            for (int r = 0; r < 4; ++r) {
                int qr = mt * 16 + quad * 4 + r;
                if (qr < 196) {
                    float v  = oa[r] * rv[r];
                    float hs = v * fminf(fmaxf(v + 3.f, 0.f), 6.f) * (1.f / 6.f);
                    obuf[(long)(bb * NTOK + qr) * DHD + hh * 128 + c] = (f16)hs;
                }
            }
        }
    }
}

__global__ __launch_bounds__(256) void bn_apply(
    float* __restrict__ out, const float* __restrict__ a2, const float* __restrict__ s2)
{
    __shared__ float aL[256], sL[256];
    int t = threadIdx.x;
    aL[t] = a2[t]; sL[t] = s2[t];
    __syncthreads();
    long total = (long)MROWS * 256 / 4;
    for (long i = (long)blockIdx.x * 256 + t; i < total; i += (long)gridDim.x * 256) {
        float4 v = *(float4*)&out[i * 4];
        int cb = (int)((i * 4) & 255);
        v.x = v.x * aL[cb + 0] + sL[cb + 0];
        v.y = v.y * aL[cb + 1] + sL[cb + 1];
        v.z = v.z * aL[cb + 2] + sL[cb + 2];
        v.w = v.w * aL[cb + 3] + sL[cb + 3];
        *(float4*)&out[i * 4] = v;
    }
}

extern "C" void kernel_launch(void* const* d_in, const int* in_sizes, int n_in,
                              void* d_out, int out_size, void* d_ws, size_t ws_size,
                              hipStream_t stream)
{
    (void)in_sizes; (void)n_in; (void)out_size; (void)ws_size;
    const float* x          = (const float*)d_in[0];
    const float* Wqkv       = (const float*)d_in[1];
    const float* g1         = (const float*)d_in[2];
    const float* b1         = (const float*)d_in[3];
    const float* bias_table = (const float*)d_in[4];
    const float* Wproj      = (const float*)d_in[5];
    const float* g2         = (const float*)d_in[6];
    const float* b2         = (const float*)d_in[7];
    const int*   idxs       = (const int*)d_in[8];
    float*       out        = (float*)d_out;

    char* ws = (char*)d_ws;
    f16* hbuf = (f16*)ws;                                 // [0, 154,140,672)
    f16* obuf = (f16*)(ws + 154140672LL);                 // [154,140,672, 256,901,120)
    f16* xh   = (f16*)(ws + 154140672LL);                 // overlay (dead before attn)
    f16* wqh  = (f16*)(ws + 154140672LL + 25690112LL);
    f16* wph  = (f16*)ws;                                 // overlay hbuf (dead after attn)
    float* stats = (float*)(ws + 256901120LL);
    float* gsum1 = stats;            float* gsq1 = stats + 1536;
    float* gsum2 = stats + 3072;     float* gsq2 = stats + 3328;
    float* a1 = stats + 3584;        float* s1 = a1 + 1536;
    float* a2 = s1 + 1536;           float* s2 = a2 + 256;
    f16* bias_full = (f16*)(ws + 256901120LL + 65536LL);  // 8*208*224*2 = 745,472 B

    hipMemsetAsync(stats, 0, 3584 * sizeof(float), stream);

    cvt_f32_f16<<<12544, 256, 0, stream>>>(x, xh, 3211264);
    cvt_f32_f16<<<384,   256, 0, stream>>>(Wqkv, wqh, 98304);
    build_bias<<<1456, 256, 0, stream>>>(bias_table, idxs, bias_full);

    gemm1_qkv<<<dim3(392, 12), 256, 0, stream>>>(xh, wqh, hbuf, gsum1, gsq1);
    bn_fin<<<6, 256, 0, stream>>>(gsum1, gsq1, g1, b1, a1, s1, 1536);

    attn_kernel<<<2048, 512, 0, stream>>>(hbuf, a1, s1, bias_full, obuf);

    cvt_f32_f16<<<256, 256, 0, stream>>>(Wproj, wph, 65536);

    gemm2_proj<<<dim3(392, 2), 256, 0, stream>>>(obuf, wph, out, gsum2, gsq2);
    bn_fin<<<1, 256, 0, stream>>>(gsum2, gsq2, g2, b2, a2, s2, 256);

    bn_apply<<<1024, 256, 0, stream>>>(out, a2, s2);
}

// Round 2
// 725.417 us; speedup vs baseline: 1.4166x; 1.4166x over previous
//
#include <hip/hip_runtime.h>

typedef _Float16 f16;
typedef __attribute__((ext_vector_type(8))) _Float16 half8;   // MFMA A/B frag (4 VGPRs)
typedef __attribute__((ext_vector_type(4))) _Float16 half4;
typedef __attribute__((ext_vector_type(4))) float   f4;       // MFMA C/D

#define NTOK   196
#define MROWS  50176            // 256 * 196
#define HIDN   1536
#define HPC    192              // per-head channels in h (q32|k32|v128)
#define DHD    1024             // H * 128
#define EPSV   1e-5f
#define SCALEV 0.17677669529663687f

// async global->LDS, 16B per lane; LDS dest is wave-uniform base + lane*16
#define GLD16(gp, lp) __builtin_amdgcn_global_load_lds( \
    (const __attribute__((address_space(1))) unsigned int*)(gp), \
    (__attribute__((address_space(3))) unsigned int*)(lp), 16, 0, 0)

// rotation swizzle: spreads banks for reads (row bits 0-3) AND writes (row bits 3-5)
__device__ inline int swz8(int row) { return (((row & 7) ^ ((row >> 3) & 7))) * 8; }

// ---------------- f32 -> f16 convert (vectorized)
__global__ void cvt_f32_f16(const float* __restrict__ src, f16* __restrict__ dst, int n4)
{
    int i = blockIdx.x * blockDim.x + threadIdx.x;
    if (i < n4) {
        float4 v = *(const float4*)&src[i * 4];
        half4 h = { (f16)v.x, (f16)v.y, (f16)v.z, (f16)v.w };
        *(half4*)&dst[i * 4] = h;
    }
}

// ---------------- bias_full[h][208][224] f16: idxs gather resolved once; pad = -30000 (mask baked in)
__global__ void build_bias(const float* __restrict__ bt, const int* __restrict__ idxs,
                           f16* __restrict__ bf)
{
    int i = blockIdx.x * 256 + threadIdx.x;
    if (i >= 8 * 208 * 224) return;
    int k = i % 224, q = (i / 224) % 208, h = i / (224 * 208);
    float v = -30000.f;
    if (q < NTOK && k < NTOK) v = bt[h * NTOK + idxs[q * NTOK + k]];
    bf[i] = (f16)v;
}

// ---------------- GEMM1: h = x @ Wqkv^T  (f16 in, f16 out + BN stats), global_load_lds staging
__global__ __launch_bounds__(256) void gemm1_qkv(
    const f16* __restrict__ A, const f16* __restrict__ B,
    f16* __restrict__ C, float* __restrict__ gsum, float* __restrict__ gsq)
{
    const int K = 256, ldc = HIDN;
    __shared__ f16 As[128 * 32];      // unpadded: required by global_load_lds layout
    __shared__ f16 Bs[128 * 32];
    __shared__ float ssum[128], ssq[128];

    const int t = threadIdx.x;
    const int m0 = blockIdx.x * 128, n0 = blockIdx.y * 128;
    const int wid = t >> 6, lane = t & 63, quad = lane >> 4, lm = lane & 15;
    const int wm = (wid >> 1) * 64, wn = (wid & 1) * 64;

    // staging geometry: wave w slot s covers rows w*32+s*16 .. +15 (lane r>>2), col8 = (lane&3)*8
    const int lr = lane >> 2, lc = (lane & 3) * 8;
    f16* As0 = &As[(wid * 2 + 0) * 512];
    f16* As1 = &As[(wid * 2 + 1) * 512];
    f16* Bs0 = &Bs[(wid * 2 + 0) * 512];
    f16* Bs1 = &Bs[(wid * 2 + 1) * 512];
    const f16* Ab = A + (long)(m0 + wid * 32 + lr) * K + lc;
    const f16* Bb = B + (long)(n0 + wid * 32 + lr) * K + lc;

    f4 acc[4][4] = {};

    for (int k0 = 0; k0 < K; k0 += 32) {
        GLD16(Ab + k0,          As0);
        GLD16(Ab + 16 * K + k0, As1);
        GLD16(Bb + k0,          Bs0);
        GLD16(Bb + 16 * K + k0, Bs1);
        __syncthreads();
        half8 a[4], b[4];
        #pragma unroll
        for (int i = 0; i < 4; ++i) a[i] = *(const half8*)&As[(wm + i*16 + lm) * 32 + quad * 8];
        #pragma unroll
        for (int j = 0; j < 4; ++j) b[j] = *(const half8*)&Bs[(wn + j*16 + lm) * 32 + quad * 8];
        #pragma unroll
        for (int i = 0; i < 4; ++i)
            #pragma unroll
            for (int j = 0; j < 4; ++j)
                acc[i][j] = __builtin_amdgcn_mfma_f32_16x16x32_f16(a[i], b[j], acc[i][j], 0, 0, 0);
        __syncthreads();
    }

    if (t < 128) { ssum[t] = 0.f; ssq[t] = 0.f; }
    __syncthreads();

    #pragma unroll
    for (int j = 0; j < 4; ++j) {
        int nl = wn + j*16 + lm;
        float psum = 0.f, psq = 0.f;
        #pragma unroll
        for (int i = 0; i < 4; ++i) {
            #pragma unroll
            for (int r = 0; r < 4; ++r) {
                int ml = wm + i*16 + quad*4 + r;
                float v = acc[i][j][r];
                f16 uh = (f16)v;
                float vb = (float)uh;
                C[(long)(m0 + ml) * ldc + n0 + nl] = uh;
                psum += vb; psq += vb * vb;
            }
        }
        atomicAdd(&ssum[nl], psum);
        atomicAdd(&ssq[nl], psq);
    }
    __syncthreads();
    if (t < 128) {
        atomicAdd(&gsum[n0 + t], ssum[t]);
        atomicAdd(&gsq[n0 + t],  ssq[t]);
    }
}

// ---------------- GEMM2: p = o @ Wproj^T  (f16 in, f32 out + BN stats), global_load_lds staging
__global__ __launch_bounds__(256) void gemm2_proj(
    const f16* __restrict__ A, const f16* __restrict__ B,
    float* __restrict__ C, float* __restrict__ gsum, float* __restrict__ gsq)
{
    const int K = 1024, ldc = 256;
    __shared__ f16 As[128 * 32];
    __shared__ f16 Bs[128 * 32];
    __shared__ float ssum[128], ssq[128];

    const int t = threadIdx.x;
    const int m0 = blockIdx.x * 128, n0 = blockIdx.y * 128;
    const int wid = t >> 6, lane = t & 63, quad = lane >> 4, lm = lane & 15;
    const int wm = (wid >> 1) * 64, wn = (wid & 1) * 64;

    const int lr = lane >> 2, lc = (lane & 3) * 8;
    f16* As0 = &As[(wid * 2 + 0) * 512];
    f16* As1 = &As[(wid * 2 + 1) * 512];
    f16* Bs0 = &Bs[(wid * 2 + 0) * 512];
    f16* Bs1 = &Bs[(wid * 2 + 1) * 512];
    const f16* Ab = A + (long)(m0 + wid * 32 + lr) * K + lc;
    const f16* Bb = B + (long)(n0 + wid * 32 + lr) * K + lc;

    f4 acc[4][4] = {};

    for (int k0 = 0; k0 < K; k0 += 32) {
        GLD16(Ab + k0,          As0);
        GLD16(Ab + 16 * K + k0, As1);
        GLD16(Bb + k0,          Bs0);
        GLD16(Bb + 16 * K + k0, Bs1);
        __syncthreads();
        half8 a[4], b[4];
        #pragma unroll
        for (int i = 0; i < 4; ++i) a[i] = *(const half8*)&As[(wm + i*16 + lm) * 32 + quad * 8];
        #pragma unroll
        for (int j = 0; j < 4; ++j) b[j] = *(const half8*)&Bs[(wn + j*16 + lm) * 32 + quad * 8];
        #pragma unroll
        for (int i = 0; i < 4; ++i)
            #pragma unroll
            for (int j = 0; j < 4; ++j)
                acc[i][j] = __builtin_amdgcn_mfma_f32_16x16x32_f16(a[i], b[j], acc[i][j], 0, 0, 0);
        __syncthreads();
    }

    if (t < 128) { ssum[t] = 0.f; ssq[t] = 0.f; }
    __syncthreads();

    #pragma unroll
    for (int j = 0; j < 4; ++j) {
        int nl = wn + j*16 + lm;
        float psum = 0.f, psq = 0.f;
        #pragma unroll
        for (int i = 0; i < 4; ++i) {
            #pragma unroll
            for (int r = 0; r < 4; ++r) {
                int ml = wm + i*16 + quad*4 + r;
                float v = acc[i][j][r];
                C[(long)(m0 + ml) * ldc + n0 + nl] = v;
                psum += v; psq += v * v;
            }
        }
        atomicAdd(&ssum[nl], psum);
        atomicAdd(&ssq[nl], psq);
    }
    __syncthreads();
    if (t < 128) {
        atomicAdd(&gsum[n0 + t], ssum[t]);
        atomicAdd(&gsq[n0 + t],  ssq[t]);
    }
}

__global__ void bn_fin(const float* __restrict__ gsum, const float* __restrict__ gsq,
                       const float* __restrict__ g, const float* __restrict__ b,
                       float* __restrict__ a_out, float* __restrict__ s_out, int nch)
{
    int c = blockIdx.x * blockDim.x + threadIdx.x;
    if (c >= nch) return;
    float inv  = 1.f / (float)MROWS;
    float mean = gsum[c] * inv;
    float var  = gsq[c] * inv - mean * mean;
    float a    = g[c] * rsqrtf(var + EPSV);
    a_out[c] = a;
    s_out[c] = b[c] - mean * a;
}

// ---------------- attention: one block (8 waves) per (batch, head).
// v3: same structure as v2 (swapped QK^T, register-resident P, no qs/ps LDS),
// but launch bound relaxed to (512, 2): this toolchain reads arg2 as min BLOCKS/CU
// (v2's (512,4) forced a 64-VGPR cap -> massive scratch spill, 1 GB scratch writes).
// (512,2) => 16 waves/CU => 128-VGPR cap; live state fits (~v1's 92), no spill,
// and LDS 80,384 B + <=128 VGPR both allow 2 blocks/CU.
__global__ __launch_bounds__(512, 2) void attn_kernel(
    const f16* __restrict__ hbuf, const float* __restrict__ a1, const float* __restrict__ s1,
    const f16* __restrict__ bf, f16* __restrict__ obuf)
{
    __shared__ f16   ks[208][32];
    __shared__ f16   vT[128][256];
    __shared__ float af[192], sf[192];

    const int t  = threadIdx.x;
    const int bb = blockIdx.x >> 3;
    const int hh = blockIdx.x & 7;
    const int wid = t >> 6, lane = t & 63, quad = lane >> 4, lm = lane & 15;

    if (t < 192) { af[t] = a1[hh * HPC + t]; sf[t] = s1[hh * HPC + t]; }
    half8 z8 = {};
    for (int i = t; i < 4096; i += 512) *(half8*)&vT[i >> 5][(i & 31) * 8] = z8;
    for (int i = t; i < 12 * 32; i += 512) ks[196 + (i >> 5)][i & 31] = (f16)0.f;
    __syncthreads();

    // stage k/v (channels 32..191) with BN1 affine, rotation-swizzled placement
    {
        int t8 = t & 7;
        for (int rr = t >> 3; rr < NTOK; rr += 64) {
            const f16* hrow = hbuf + (long)(bb * NTOK + rr) * HIDN + hh * HPC;
            int sr = swz8(rr);
            #pragma unroll
            for (int cc = 0; cc < 3; ++cc) {
                int cb = 32 + (t8 + cc * 8) * 8;   // 32..216 step 8; skip >=192
                if (cb >= 192) continue;
                half8 raw = *(const half8*)(hrow + cb);
                f16 ov[8];
                #pragma unroll
                for (int e = 0; e < 8; ++e)
                    ov[e] = (f16)((float)raw[e] * af[cb + e] + sf[cb + e]);
                if (cb < 64) {
                    #pragma unroll
                    for (int e = 0; e < 8; ++e) ks[rr][(cb - 32 + e + sr) & 31] = ov[e];
                } else {
                    #pragma unroll
                    for (int e = 0; e < 8; ++e) {
                        int c = cb - 64 + e;
                        vT[c][(rr + swz8(c)) & 255] = ov[e];
                    }
                }
            }
        }
    }
    __syncthreads();

    const int nmt = (wid + 8 < 13) ? 2 : 1;
    const f16* bfh = bf + hh * 208 * 224;

    for (int pass = 0; pass < nmt; ++pass) {
        const int mt = wid + pass * 8;
        const int qrow = mt * 16 + lm;                       // 0..207 (>=196 masked rows)

        // ---- q B-frag direct from global + BN1 affine (q = channels 0..31)
        long grow = (long)bb * NTOK + qrow;
        if (grow > (long)(MROWS - 1)) grow = MROWS - 1;      // clamp tail OOB (values masked)
        half8 qraw = *(const half8*)(hbuf + grow * HIDN + hh * HPC + quad * 8);
        half8 qf;
        #pragma unroll
        for (int e = 0; e < 8; ++e)
            qf[e] = (f16)((float)qraw[e] * af[quad * 8 + e] + sf[quad * 8 + e]);

        // ---- S^T = K·Q^T (13 MFMAs). Lane holds q = qrow (col=lm), k = nt*16 + quad*4 + r.
        f4 sreg[13];
        #pragma unroll
        for (int nt = 0; nt < 13; ++nt) {
            int krow = nt * 16 + lm;
            half8 ak = *(const half8*)&ks[krow][(quad * 8 + swz8(krow)) & 31];
            f4 z = {};
            sreg[nt] = __builtin_amdgcn_mfma_f32_16x16x32_f16(ak, qf, z, 0, 0, 0);
        }

        // ---- scale + bias (mask baked into bias pad rows/cols), running max
        const f16* brow = bfh + qrow * 224 + quad * 4;
        float m = -3.0e38f;
        #pragma unroll
        for (int nt = 0; nt < 13; ++nt) {
            half4 b4 = *(const half4*)(brow + nt * 16);
            #pragma unroll
            for (int r = 0; r < 4; ++r) {
                sreg[nt][r] = sreg[nt][r] * SCALEV + (float)b4[r];
                m = fmaxf(m, sreg[nt][r]);
            }
        }
        m = fmaxf(m, __shfl_xor(m, 16));
        m = fmaxf(m, __shfl_xor(m, 32));

        // ---- exp + sum; P stays unnormalized (<=1) in registers as PV A-frags
        float s = 0.f;
        half4 ap[13];
        #pragma unroll
        for (int nt = 0; nt < 13; ++nt) {
            float e0 = __expf(sreg[nt][0] - m);
            float e1 = __expf(sreg[nt][1] - m);
            float e2 = __expf(sreg[nt][2] - m);
            float e3 = __expf(sreg[nt][3] - m);
            s += (e0 + e1) + (e2 + e3);
            ap[nt] = half4{ (f16)e0, (f16)e1, (f16)e2, (f16)e3 };
        }
        s += __shfl_xor(s, 16);
        s += __shfl_xor(s, 32);
        float rinv = 1.f / s;

        // redistribute rinv to output layout (row = quad*4+r)
        float rv[4];
        #pragma unroll
        for (int r = 0; r < 4; ++r) rv[r] = __shfl(rinv, quad * 4 + r);

        // ---- O = P·V via 16x16x16 (A-frag = ap, matches register layout exactly)
        #pragma unroll
        for (int ct = 0; ct < 8; ++ct) {
            int c = ct * 16 + lm;
            int sc = swz8(c);
            f4 oa = {};
            #pragma unroll
            for (int nt = 0; nt < 13; ++nt) {
                half4 bv = *(const half4*)&vT[c][(nt * 16 + quad * 4 + sc) & 255];
                oa = __builtin_amdgcn_mfma_f32_16x16x16f16(ap[nt], bv, oa, 0, 0, 0);
            }
            #pragma unroll
            for (int r = 0; r < 4; ++r) {
                int qr = mt * 16 + quad * 4 + r;
                if (qr < 196) {
                    float v  = oa[r] * rv[r];
                    float hs = v * fminf(fmaxf(v + 3.f, 0.f), 6.f) * (1.f / 6.f);
                    obuf[(long)(bb * NTOK + qr) * DHD + hh * 128 + c] = (f16)hs;
                }
            }
        }
    }
}

__global__ __launch_bounds__(256) void bn_apply(
    float* __restrict__ out, const float* __restrict__ a2, const float* __restrict__ s2)
{
    __shared__ float aL[256], sL[256];
    int t = threadIdx.x;
    aL[t] = a2[t]; sL[t] = s2[t];
    __syncthreads();
    long total = (long)MROWS * 256 / 4;
    for (long i = (long)blockIdx.x * 256 + t; i < total; i += (long)gridDim.x * 256) {
        float4 v = *(float4*)&out[i * 4];
        int cb = (int)((i * 4) & 255);
        v.x = v.x * aL[cb + 0] + sL[cb + 0];
        v.y = v.y * aL[cb + 1] + sL[cb + 1];
        v.z = v.z * aL[cb + 2] + sL[cb + 2];
        v.w = v.w * aL[cb + 3] + sL[cb + 3];
        *(float4*)&out[i * 4] = v;
    }
}

extern "C" void kernel_launch(void* const* d_in, const int* in_sizes, int n_in,
                              void* d_out, int out_size, void* d_ws, size_t ws_size,
                              hipStream_t stream)
{
    (void)in_sizes; (void)n_in; (void)out_size; (void)ws_size;
    const float* x          = (const float*)d_in[0];
    const float* Wqkv       = (const float*)d_in[1];
    const float* g1         = (const float*)d_in[2];
    const float* b1         = (const float*)d_in[3];
    const float* bias_table = (const float*)d_in[4];
    const float* Wproj      = (const float*)d_in[5];
    const float* g2         = (const float*)d_in[6];
    const float* b2         = (const float*)d_in[7];
    const int*   idxs       = (const int*)d_in[8];
    float*       out        = (float*)d_out;

    char* ws = (char*)d_ws;
    f16* hbuf = (f16*)ws;                                 // [0, 154,140,672)
    f16* obuf = (f16*)(ws + 154140672LL);                 // [154,140,672, 256,901,120)
    f16* xh   = (f16*)(ws + 154140672LL);                 // overlay (dead before attn)
    f16* wqh  = (f16*)(ws + 154140672LL + 25690112LL);
    f16* wph  = (f16*)ws;                                 // overlay hbuf (dead after attn)
    float* stats = (float*)(ws + 256901120LL);
    float* gsum1 = stats;            float* gsq1 = stats + 1536;
    float* gsum2 = stats + 3072;     float* gsq2 = stats + 3328;
    float* a1 = stats + 3584;        float* s1 = a1 + 1536;
    float* a2 = s1 + 1536;           float* s2 = a2 + 256;
    f16* bias_full = (f16*)(ws + 256901120LL + 65536LL);  // 8*208*224*2 = 745,472 B

    hipMemsetAsync(stats, 0, 3584 * sizeof(float), stream);

    cvt_f32_f16<<<12544, 256, 0, stream>>>(x, xh, 3211264);
    cvt_f32_f16<<<384,   256, 0, stream>>>(Wqkv, wqh, 98304);
    build_bias<<<1456, 256, 0, stream>>>(bias_table, idxs, bias_full);

    gemm1_qkv<<<dim3(392, 12), 256, 0, stream>>>(xh, wqh, hbuf, gsum1, gsq1);
    bn_fin<<<6, 256, 0, stream>>>(gsum1, gsq1, g1, b1, a1, s1, 1536);

    attn_kernel<<<2048, 512, 0, stream>>>(hbuf, a1, s1, bias_full, obuf);

    cvt_f32_f16<<<256, 256, 0, stream>>>(Wproj, wph, 65536);

    gemm2_proj<<<dim3(392, 2), 256, 0, stream>>>(obuf, wph, out, gsum2, gsq2);
    bn_fin<<<1, 256, 0, stream>>>(gsum2, gsq2, g2, b2, a2, s2, 256);

    bn_apply<<<1024, 256, 0, stream>>>(out, a2, s2);
}

// Round 3
// 494.851 us; speedup vs baseline: 2.0766x; 1.4659x over previous
//
#include <hip/hip_runtime.h>

typedef _Float16 f16;
typedef __attribute__((ext_vector_type(8))) _Float16 half8;   // MFMA A/B frag (4 VGPRs)
typedef __attribute__((ext_vector_type(4))) _Float16 half4;
typedef __attribute__((ext_vector_type(4))) float   f4;       // MFMA C/D

#define NTOK   196
#define MROWS  50176            // 256 * 196
#define HIDN   1536
#define HPC    192              // per-head channels in h (q32|k32|v128)
#define DHD    1024             // H * 128
#define EPSV   1e-5f
#define SCALEV 0.17677669529663687f

// async global->LDS, 16B per lane; LDS dest is wave-uniform base + lane*16
#define GLD16(gp, lp) __builtin_amdgcn_global_load_lds( \
    (const __attribute__((address_space(1))) unsigned int*)(gp), \
    (__attribute__((address_space(3))) unsigned int*)(lp), 16, 0, 0)

// rotation swizzle: spreads banks for reads (row bits 0-3) AND writes (row bits 3-5)
__device__ inline int swz8(int row) { return (((row & 7) ^ ((row >> 3) & 7))) * 8; }

// ---------------- f32 -> f16 convert (vectorized)
__global__ void cvt_f32_f16(const float* __restrict__ src, f16* __restrict__ dst, int n4)
{
    int i = blockIdx.x * blockDim.x + threadIdx.x;
    if (i < n4) {
        float4 v = *(const float4*)&src[i * 4];
        half4 h = { (f16)v.x, (f16)v.y, (f16)v.z, (f16)v.w };
        *(half4*)&dst[i * 4] = h;
    }
}

// ---------------- bias_full[h][208][224] f16: idxs gather resolved once; pad = -30000 (mask baked in)
__global__ void build_bias(const float* __restrict__ bt, const int* __restrict__ idxs,
                           f16* __restrict__ bf)
{
    int i = blockIdx.x * 256 + threadIdx.x;
    if (i >= 8 * 208 * 224) return;
    int k = i % 224, q = (i / 224) % 208, h = i / (224 * 208);
    float v = -30000.f;
    if (q < NTOK && k < NTOK) v = bt[h * NTOK + idxs[q * NTOK + k]];
    bf[i] = (f16)v;
}

// ---------------- GEMM1: h = x @ Wqkv^T  (f16 in, f16 out + BN stats), global_load_lds staging
__global__ __launch_bounds__(256) void gemm1_qkv(
    const f16* __restrict__ A, const f16* __restrict__ B,
    f16* __restrict__ C, float* __restrict__ gsum, float* __restrict__ gsq)
{
    const int K = 256, ldc = HIDN;
    __shared__ f16 As[128 * 32];      // unpadded: required by global_load_lds layout
    __shared__ f16 Bs[128 * 32];
    __shared__ float ssum[128], ssq[128];

    const int t = threadIdx.x;
    const int m0 = blockIdx.x * 128, n0 = blockIdx.y * 128;
    const int wid = t >> 6, lane = t & 63, quad = lane >> 4, lm = lane & 15;
    const int wm = (wid >> 1) * 64, wn = (wid & 1) * 64;

    // staging geometry: wave w slot s covers rows w*32+s*16 .. +15 (lane r>>2), col8 = (lane&3)*8
    const int lr = lane >> 2, lc = (lane & 3) * 8;
    f16* As0 = &As[(wid * 2 + 0) * 512];
    f16* As1 = &As[(wid * 2 + 1) * 512];
    f16* Bs0 = &Bs[(wid * 2 + 0) * 512];
    f16* Bs1 = &Bs[(wid * 2 + 1) * 512];
    const f16* Ab = A + (long)(m0 + wid * 32 + lr) * K + lc;
    const f16* Bb = B + (long)(n0 + wid * 32 + lr) * K + lc;

    f4 acc[4][4] = {};

    for (int k0 = 0; k0 < K; k0 += 32) {
        GLD16(Ab + k0,          As0);
        GLD16(Ab + 16 * K + k0, As1);
        GLD16(Bb + k0,          Bs0);
        GLD16(Bb + 16 * K + k0, Bs1);
        __syncthreads();
        half8 a[4], b[4];
        #pragma unroll
        for (int i = 0; i < 4; ++i) a[i] = *(const half8*)&As[(wm + i*16 + lm) * 32 + quad * 8];
        #pragma unroll
        for (int j = 0; j < 4; ++j) b[j] = *(const half8*)&Bs[(wn + j*16 + lm) * 32 + quad * 8];
        #pragma unroll
        for (int i = 0; i < 4; ++i)
            #pragma unroll
            for (int j = 0; j < 4; ++j)
                acc[i][j] = __builtin_amdgcn_mfma_f32_16x16x32_f16(a[i], b[j], acc[i][j], 0, 0, 0);
        __syncthreads();
    }

    if (t < 128) { ssum[t] = 0.f; ssq[t] = 0.f; }
    __syncthreads();

    #pragma unroll
    for (int j = 0; j < 4; ++j) {
        int nl = wn + j*16 + lm;
        float psum = 0.f, psq = 0.f;
        #pragma unroll
        for (int i = 0; i < 4; ++i) {
            #pragma unroll
            for (int r = 0; r < 4; ++r) {
                int ml = wm + i*16 + quad*4 + r;
                float v = acc[i][j][r];
                f16 uh = (f16)v;
                float vb = (float)uh;
                C[(long)(m0 + ml) * ldc + n0 + nl] = uh;
                psum += vb; psq += vb * vb;
            }
        }
        atomicAdd(&ssum[nl], psum);
        atomicAdd(&ssq[nl], psq);
    }
    __syncthreads();
    if (t < 128) {
        atomicAdd(&gsum[n0 + t], ssum[t]);
        atomicAdd(&gsq[n0 + t],  ssq[t]);
    }
}

// ---------------- GEMM2: p = o @ Wproj^T  (f16 in, f32 out + BN stats), global_load_lds staging
__global__ __launch_bounds__(256) void gemm2_proj(
    const f16* __restrict__ A, const f16* __restrict__ B,
    float* __restrict__ C, float* __restrict__ gsum, float* __restrict__ gsq)
{
    const int K = 1024, ldc = 256;
    __shared__ f16 As[128 * 32];
    __shared__ f16 Bs[128 * 32];
    __shared__ float ssum[128], ssq[128];

    const int t = threadIdx.x;
    const int m0 = blockIdx.x * 128, n0 = blockIdx.y * 128;
    const int wid = t >> 6, lane = t & 63, quad = lane >> 4, lm = lane & 15;
    const int wm = (wid >> 1) * 64, wn = (wid & 1) * 64;

    const int lr = lane >> 2, lc = (lane & 3) * 8;
    f16* As0 = &As[(wid * 2 + 0) * 512];
    f16* As1 = &As[(wid * 2 + 1) * 512];
    f16* Bs0 = &Bs[(wid * 2 + 0) * 512];
    f16* Bs1 = &Bs[(wid * 2 + 1) * 512];
    const f16* Ab = A + (long)(m0 + wid * 32 + lr) * K + lc;
    const f16* Bb = B + (long)(n0 + wid * 32 + lr) * K + lc;

    f4 acc[4][4] = {};

    for (int k0 = 0; k0 < K; k0 += 32) {
        GLD16(Ab + k0,          As0);
        GLD16(Ab + 16 * K + k0, As1);
        GLD16(Bb + k0,          Bs0);
        GLD16(Bb + 16 * K + k0, Bs1);
        __syncthreads();
        half8 a[4], b[4];
        #pragma unroll
        for (int i = 0; i < 4; ++i) a[i] = *(const half8*)&As[(wm + i*16 + lm) * 32 + quad * 8];
        #pragma unroll
        for (int j = 0; j < 4; ++j) b[j] = *(const half8*)&Bs[(wn + j*16 + lm) * 32 + quad * 8];
        #pragma unroll
        for (int i = 0; i < 4; ++i)
            #pragma unroll
            for (int j = 0; j < 4; ++j)
                acc[i][j] = __builtin_amdgcn_mfma_f32_16x16x32_f16(a[i], b[j], acc[i][j], 0, 0, 0);
        __syncthreads();
    }

    if (t < 128) { ssum[t] = 0.f; ssq[t] = 0.f; }
    __syncthreads();

    #pragma unroll
    for (int j = 0; j < 4; ++j) {
        int nl = wn + j*16 + lm;
        float psum = 0.f, psq = 0.f;
        #pragma unroll
        for (int i = 0; i < 4; ++i) {
            #pragma unroll
            for (int r = 0; r < 4; ++r) {
                int ml = wm + i*16 + quad*4 + r;
                float v = acc[i][j][r];
                C[(long)(m0 + ml) * ldc + n0 + nl] = v;
                psum += v; psq += v * v;
            }
        }
        atomicAdd(&ssum[nl], psum);
        atomicAdd(&ssq[nl], psq);
    }
    __syncthreads();
    if (t < 128) {
        atomicAdd(&gsum[n0 + t], ssum[t]);
        atomicAdd(&gsq[n0 + t],  ssq[t]);
    }
}

__global__ void bn_fin(const float* __restrict__ gsum, const float* __restrict__ gsq,
                       const float* __restrict__ g, const float* __restrict__ b,
                       float* __restrict__ a_out, float* __restrict__ s_out, int nch)
{
    int c = blockIdx.x * blockDim.x + threadIdx.x;
    if (c >= nch) return;
    float inv  = 1.f / (float)MROWS;
    float mean = gsum[c] * inv;
    float var  = gsq[c] * inv - mean * mean;
    float a    = g[c] * rsqrtf(var + EPSV);
    a_out[c] = a;
    s_out[c] = b[c] - mean * a;
}

// ---------------- attention: one block (8 waves) per (batch, head).
// v4: v3 structure (swapped QK^T, register-resident P, no qs/ps LDS, 2 blocks/CU)
// + two-pass softmax with QK^T RECOMPUTE. v3 spilled at the 128-VGPR cap because
// sreg[13] (52 f32 regs) stayed live from QK^T through the max reduction, on top
// of hoisted LDS loads. Pass A now computes the 13 MFMAs only for the running max
// (each S-tile dies immediately); pass B recomputes them and goes straight to
// exp -> f16 ap[13] (26 regs). MFMA pipe is at 5% util - the recompute is free.
// A compiler barrier between passes blocks CSE from resurrecting the S values.
__global__ __launch_bounds__(512, 2) void attn_kernel(
    const f16* __restrict__ hbuf, const float* __restrict__ a1, const float* __restrict__ s1,
    const f16* __restrict__ bf, f16* __restrict__ obuf)
{
    __shared__ f16   ks[208][32];
    __shared__ f16   vT[128][256];
    __shared__ float af[192], sf[192];

    const int t  = threadIdx.x;
    const int bb = blockIdx.x >> 3;
    const int hh = blockIdx.x & 7;
    const int wid = t >> 6, lane = t & 63, quad = lane >> 4, lm = lane & 15;

    if (t < 192) { af[t] = a1[hh * HPC + t]; sf[t] = s1[hh * HPC + t]; }
    half8 z8 = {};
    for (int i = t; i < 4096; i += 512) *(half8*)&vT[i >> 5][(i & 31) * 8] = z8;
    for (int i = t; i < 12 * 32; i += 512) ks[196 + (i >> 5)][i & 31] = (f16)0.f;
    __syncthreads();

    // stage k/v (channels 32..191) with BN1 affine, rotation-swizzled placement
    {
        int t8 = t & 7;
        for (int rr = t >> 3; rr < NTOK; rr += 64) {
            const f16* hrow = hbuf + (long)(bb * NTOK + rr) * HIDN + hh * HPC;
            int sr = swz8(rr);
            #pragma unroll
            for (int cc = 0; cc < 3; ++cc) {
                int cb = 32 + (t8 + cc * 8) * 8;   // 32..216 step 8; skip >=192
                if (cb >= 192) continue;
                half8 raw = *(const half8*)(hrow + cb);
                f16 ov[8];
                #pragma unroll
                for (int e = 0; e < 8; ++e)
                    ov[e] = (f16)((float)raw[e] * af[cb + e] + sf[cb + e]);
                if (cb < 64) {
                    #pragma unroll
                    for (int e = 0; e < 8; ++e) ks[rr][(cb - 32 + e + sr) & 31] = ov[e];
                } else {
                    #pragma unroll
                    for (int e = 0; e < 8; ++e) {
                        int c = cb - 64 + e;
                        vT[c][(rr + swz8(c)) & 255] = ov[e];
                    }
                }
            }
        }
    }
    __syncthreads();

    const int nmt = (wid + 8 < 13) ? 2 : 1;
    const f16* bfh = bf + hh * 208 * 224;

    for (int pass = 0; pass < nmt; ++pass) {
        const int mt = wid + pass * 8;
        const int qrow = mt * 16 + lm;                       // 0..207 (>=196 masked rows)

        // ---- q B-frag direct from global + BN1 affine (q = channels 0..31)
        long grow = (long)bb * NTOK + qrow;
        if (grow > (long)(MROWS - 1)) grow = MROWS - 1;      // clamp tail OOB (values masked)
        half8 qraw = *(const half8*)(hbuf + grow * HIDN + hh * HPC + quad * 8);
        half8 qf;
        #pragma unroll
        for (int e = 0; e < 8; ++e)
            qf[e] = (f16)((float)qraw[e] * af[quad * 8 + e] + sf[quad * 8 + e]);

        const f16* brow = bfh + qrow * 224 + quad * 4;

        // ---- pass A: S^T = K*Q^T tiles, keep only the running max (S dies per-tile)
        float m = -3.0e38f;
        #pragma unroll
        for (int nt = 0; nt < 13; ++nt) {
            int krow = nt * 16 + lm;
            half8 ak = *(const half8*)&ks[krow][(quad * 8 + swz8(krow)) & 31];
            f4 z = {};
            f4 s4 = __builtin_amdgcn_mfma_f32_16x16x32_f16(ak, qf, z, 0, 0, 0);
            half4 b4 = *(const half4*)(brow + nt * 16);
            float v0 = fmaf(s4[0], SCALEV, (float)b4[0]);
            float v1 = fmaf(s4[1], SCALEV, (float)b4[1]);
            float v2 = fmaf(s4[2], SCALEV, (float)b4[2]);
            float v3 = fmaf(s4[3], SCALEV, (float)b4[3]);
            m = fmaxf(m, fmaxf(fmaxf(v0, v1), fmaxf(v2, v3)));
        }
        m = fmaxf(m, __shfl_xor(m, 16));
        m = fmaxf(m, __shfl_xor(m, 32));

        // block CSE/reordering across the passes: without this the compiler reuses
        // pass-A S values and re-creates the 52-reg live range that spilled in v3
        asm volatile("" ::: "memory");

        // ---- pass B: recompute S, exp, sum; P stays unnormalized (<=1) f16 in regs
        float s = 0.f;
        half4 ap[13];
        #pragma unroll
        for (int nt = 0; nt < 13; ++nt) {
            int krow = nt * 16 + lm;
            half8 ak = *(const half8*)&ks[krow][(quad * 8 + swz8(krow)) & 31];
            f4 z = {};
            f4 s4 = __builtin_amdgcn_mfma_f32_16x16x32_f16(ak, qf, z, 0, 0, 0);
            half4 b4 = *(const half4*)(brow + nt * 16);
            float e0 = __expf(fmaf(s4[0], SCALEV, (float)b4[0]) - m);
            float e1 = __expf(fmaf(s4[1], SCALEV, (float)b4[1]) - m);
            float e2 = __expf(fmaf(s4[2], SCALEV, (float)b4[2]) - m);
            float e3 = __expf(fmaf(s4[3], SCALEV, (float)b4[3]) - m);
            s += (e0 + e1) + (e2 + e3);
            ap[nt] = half4{ (f16)e0, (f16)e1, (f16)e2, (f16)e3 };
        }
        s += __shfl_xor(s, 16);
        s += __shfl_xor(s, 32);
        float rinv = 1.f / s;

        // redistribute rinv to output layout (row = quad*4+r)
        float rv[4];
        #pragma unroll
        for (int r = 0; r < 4; ++r) rv[r] = __shfl(rinv, quad * 4 + r);

        // ---- O = P·V via 16x16x16 (A-frag = ap, matches register layout exactly)
        #pragma unroll
        for (int ct = 0; ct < 8; ++ct) {
            int c = ct * 16 + lm;
            int sc = swz8(c);
            f4 oa = {};
            #pragma unroll
            for (int nt = 0; nt < 13; ++nt) {
                half4 bv = *(const half4*)&vT[c][(nt * 16 + quad * 4 + sc) & 255];
                oa = __builtin_amdgcn_mfma_f32_16x16x16f16(ap[nt], bv, oa, 0, 0, 0);
            }
            #pragma unroll
            for (int r = 0; r < 4; ++r) {
                int qr = mt * 16 + quad * 4 + r;
                if (qr < 196) {
                    float v  = oa[r] * rv[r];
                    float hs = v * fminf(fmaxf(v + 3.f, 0.f), 6.f) * (1.f / 6.f);
                    obuf[(long)(bb * NTOK + qr) * DHD + hh * 128 + c] = (f16)hs;
                }
            }
        }
    }
}

__global__ __launch_bounds__(256) void bn_apply(
    float* __restrict__ out, const float* __restrict__ a2, const float* __restrict__ s2)
{
    __shared__ float aL[256], sL[256];
    int t = threadIdx.x;
    aL[t] = a2[t]; sL[t] = s2[t];
    __syncthreads();
    long total = (long)MROWS * 256 / 4;
    for (long i = (long)blockIdx.x * 256 + t; i < total; i += (long)gridDim.x * 256) {
        float4 v = *(float4*)&out[i * 4];
        int cb = (int)((i * 4) & 255);
        v.x = v.x * aL[cb + 0] + sL[cb + 0];
        v.y = v.y * aL[cb + 1] + sL[cb + 1];
        v.z = v.z * aL[cb + 2] + sL[cb + 2];
        v.w = v.w * aL[cb + 3] + sL[cb + 3];
        *(float4*)&out[i * 4] = v;
    }
}

extern "C" void kernel_launch(void* const* d_in, const int* in_sizes, int n_in,
                              void* d_out, int out_size, void* d_ws, size_t ws_size,
                              hipStream_t stream)
{
    (void)in_sizes; (void)n_in; (void)out_size; (void)ws_size;
    const float* x          = (const float*)d_in[0];
    const float* Wqkv       = (const float*)d_in[1];
    const float* g1         = (const float*)d_in[2];
    const float* b1         = (const float*)d_in[3];
    const float* bias_table = (const float*)d_in[4];
    const float* Wproj      = (const float*)d_in[5];
    const float* g2         = (const float*)d_in[6];
    const float* b2         = (const float*)d_in[7];
    const int*   idxs       = (const int*)d_in[8];
    float*       out        = (float*)d_out;

    char* ws = (char*)d_ws;
    f16* hbuf = (f16*)ws;                                 // [0, 154,140,672)
    f16* obuf = (f16*)(ws + 154140672LL);                 // [154,140,672, 256,901,120)
    f16* xh   = (f16*)(ws + 154140672LL);                 // overlay (dead before attn)
    f16* wqh  = (f16*)(ws + 154140672LL + 25690112LL);
    f16* wph  = (f16*)ws;                                 // overlay hbuf (dead after attn)
    float* stats = (float*)(ws + 256901120LL);
    float* gsum1 = stats;            float* gsq1 = stats + 1536;
    float* gsum2 = stats + 3072;     float* gsq2 = stats + 3328;
    float* a1 = stats + 3584;        float* s1 = a1 + 1536;
    float* a2 = s1 + 1536;           float* s2 = a2 + 256;
    f16* bias_full = (f16*)(ws + 256901120LL + 65536LL);  // 8*208*224*2 = 745,472 B

    hipMemsetAsync(stats, 0, 3584 * sizeof(float), stream);

    cvt_f32_f16<<<12544, 256, 0, stream>>>(x, xh, 3211264);
    cvt_f32_f16<<<384,   256, 0, stream>>>(Wqkv, wqh, 98304);
    build_bias<<<1456, 256, 0, stream>>>(bias_table, idxs, bias_full);

    gemm1_qkv<<<dim3(392, 12), 256, 0, stream>>>(xh, wqh, hbuf, gsum1, gsq1);
    bn_fin<<<6, 256, 0, stream>>>(gsum1, gsq1, g1, b1, a1, s1, 1536);

    attn_kernel<<<2048, 512, 0, stream>>>(hbuf, a1, s1, bias_full, obuf);

    cvt_f32_f16<<<256, 256, 0, stream>>>(Wproj, wph, 65536);

    gemm2_proj<<<dim3(392, 2), 256, 0, stream>>>(obuf, wph, out, gsum2, gsq2);
    bn_fin<<<1, 256, 0, stream>>>(gsum2, gsq2, g2, b2, a2, s2, 256);

    bn_apply<<<1024, 256, 0, stream>>>(out, a2, s2);
}

// Round 4
// 449.173 us; speedup vs baseline: 2.2878x; 1.1017x over previous
//
#include <hip/hip_runtime.h>

typedef _Float16 f16;
typedef __attribute__((ext_vector_type(8))) _Float16 half8;   // MFMA A/B frag (4 VGPRs)
typedef __attribute__((ext_vector_type(4))) _Float16 half4;
typedef __attribute__((ext_vector_type(4))) float   f4;       // MFMA C/D

#define NTOK   196
#define MROWS  50176            // 256 * 196
#define HIDN   1536
#define HPC    192              // per-head channels in h (q32|k32|v128)
#define DHD    1024             // H * 128
#define EPSV   1e-5f
#define SCALEV 0.17677669529663687f

// async global->LDS, 16B per lane; LDS dest is wave-uniform base + lane*16
#define GLD16(gp, lp) __builtin_amdgcn_global_load_lds( \
    (const __attribute__((address_space(1))) unsigned int*)(gp), \
    (__attribute__((address_space(3))) unsigned int*)(lp), 16, 0, 0)

// rotation swizzle: spreads banks for reads (row bits 0-3) AND writes (row bits 3-5)
__device__ inline int swz8(int row) { return (((row & 7) ^ ((row >> 3) & 7))) * 8; }

// ---------------- f32 -> f16 convert (vectorized)
__global__ void cvt_f32_f16(const float* __restrict__ src, f16* __restrict__ dst, int n4)
{
    int i = blockIdx.x * blockDim.x + threadIdx.x;
    if (i < n4) {
        float4 v = *(const float4*)&src[i * 4];
        half4 h = { (f16)v.x, (f16)v.y, (f16)v.z, (f16)v.w };
        *(half4*)&dst[i * 4] = h;
    }
}

// ---------------- bias_full[h][208][224] f16: idxs gather resolved once; pad = -30000 (mask baked in)
__global__ void build_bias(const float* __restrict__ bt, const int* __restrict__ idxs,
                           f16* __restrict__ bf)
{
    int i = blockIdx.x * 256 + threadIdx.x;
    if (i >= 8 * 208 * 224) return;
    int k = i % 224, q = (i / 224) % 208, h = i / (224 * 208);
    float v = -30000.f;
    if (q < NTOK && k < NTOK) v = bt[h * NTOK + idxs[q * NTOK + k]];
    bf[i] = (f16)v;
}

// ---------------- GEMM1: h = x @ Wqkv^T  (f16 in, f16 out + BN stats), global_load_lds staging
__global__ __launch_bounds__(256) void gemm1_qkv(
    const f16* __restrict__ A, const f16* __restrict__ B,
    f16* __restrict__ C, float* __restrict__ gsum, float* __restrict__ gsq)
{
    const int K = 256, ldc = HIDN;
    __shared__ f16 As[128 * 32];      // unpadded: required by global_load_lds layout
    __shared__ f16 Bs[128 * 32];
    __shared__ float ssum[128], ssq[128];

    const int t = threadIdx.x;
    const int m0 = blockIdx.x * 128, n0 = blockIdx.y * 128;
    const int wid = t >> 6, lane = t & 63, quad = lane >> 4, lm = lane & 15;
    const int wm = (wid >> 1) * 64, wn = (wid & 1) * 64;

    // staging geometry: wave w slot s covers rows w*32+s*16 .. +15 (lane r>>2), col8 = (lane&3)*8
    const int lr = lane >> 2, lc = (lane & 3) * 8;
    f16* As0 = &As[(wid * 2 + 0) * 512];
    f16* As1 = &As[(wid * 2 + 1) * 512];
    f16* Bs0 = &Bs[(wid * 2 + 0) * 512];
    f16* Bs1 = &Bs[(wid * 2 + 1) * 512];
    const f16* Ab = A + (long)(m0 + wid * 32 + lr) * K + lc;
    const f16* Bb = B + (long)(n0 + wid * 32 + lr) * K + lc;

    f4 acc[4][4] = {};

    for (int k0 = 0; k0 < K; k0 += 32) {
        GLD16(Ab + k0,          As0);
        GLD16(Ab + 16 * K + k0, As1);
        GLD16(Bb + k0,          Bs0);
        GLD16(Bb + 16 * K + k0, Bs1);
        __syncthreads();
        half8 a[4], b[4];
        #pragma unroll
        for (int i = 0; i < 4; ++i) a[i] = *(const half8*)&As[(wm + i*16 + lm) * 32 + quad * 8];
        #pragma unroll
        for (int j = 0; j < 4; ++j) b[j] = *(const half8*)&Bs[(wn + j*16 + lm) * 32 + quad * 8];
        #pragma unroll
        for (int i = 0; i < 4; ++i)
            #pragma unroll
            for (int j = 0; j < 4; ++j)
                acc[i][j] = __builtin_amdgcn_mfma_f32_16x16x32_f16(a[i], b[j], acc[i][j], 0, 0, 0);
        __syncthreads();
    }

    if (t < 128) { ssum[t] = 0.f; ssq[t] = 0.f; }
    __syncthreads();

    #pragma unroll
    for (int j = 0; j < 4; ++j) {
        int nl = wn + j*16 + lm;
        float psum = 0.f, psq = 0.f;
        #pragma unroll
        for (int i = 0; i < 4; ++i) {
            #pragma unroll
            for (int r = 0; r < 4; ++r) {
                int ml = wm + i*16 + quad*4 + r;
                float v = acc[i][j][r];
                f16 uh = (f16)v;
                float vb = (float)uh;
                C[(long)(m0 + ml) * ldc + n0 + nl] = uh;
                psum += vb; psq += vb * vb;
            }
        }
        atomicAdd(&ssum[nl], psum);
        atomicAdd(&ssq[nl], psq);
    }
    __syncthreads();
    if (t < 128) {
        atomicAdd(&gsum[n0 + t], ssum[t]);
        atomicAdd(&gsq[n0 + t],  ssq[t]);
    }
}

// ---------------- GEMM2: p = o @ Wproj^T  (f16 in, f32 out + BN stats), global_load_lds staging
__global__ __launch_bounds__(256) void gemm2_proj(
    const f16* __restrict__ A, const f16* __restrict__ B,
    float* __restrict__ C, float* __restrict__ gsum, float* __restrict__ gsq)
{
    const int K = 1024, ldc = 256;
    __shared__ f16 As[128 * 32];
    __shared__ f16 Bs[128 * 32];
    __shared__ float ssum[128], ssq[128];

    const int t = threadIdx.x;
    const int m0 = blockIdx.x * 128, n0 = blockIdx.y * 128;
    const int wid = t >> 6, lane = t & 63, quad = lane >> 4, lm = lane & 15;
    const int wm = (wid >> 1) * 64, wn = (wid & 1) * 64;

    const int lr = lane >> 2, lc = (lane & 3) * 8;
    f16* As0 = &As[(wid * 2 + 0) * 512];
    f16* As1 = &As[(wid * 2 + 1) * 512];
    f16* Bs0 = &Bs[(wid * 2 + 0) * 512];
    f16* Bs1 = &Bs[(wid * 2 + 1) * 512];
    const f16* Ab = A + (long)(m0 + wid * 32 + lr) * K + lc;
    const f16* Bb = B + (long)(n0 + wid * 32 + lr) * K + lc;

    f4 acc[4][4] = {};

    for (int k0 = 0; k0 < K; k0 += 32) {
        GLD16(Ab + k0,          As0);
        GLD16(Ab + 16 * K + k0, As1);
        GLD16(Bb + k0,          Bs0);
        GLD16(Bb + 16 * K + k0, Bs1);
        __syncthreads();
        half8 a[4], b[4];
        #pragma unroll
        for (int i = 0; i < 4; ++i) a[i] = *(const half8*)&As[(wm + i*16 + lm) * 32 + quad * 8];
        #pragma unroll
        for (int j = 0; j < 4; ++j) b[j] = *(const half8*)&Bs[(wn + j*16 + lm) * 32 + quad * 8];
        #pragma unroll
        for (int i = 0; i < 4; ++i)
            #pragma unroll
            for (int j = 0; j < 4; ++j)
                acc[i][j] = __builtin_amdgcn_mfma_f32_16x16x32_f16(a[i], b[j], acc[i][j], 0, 0, 0);
        __syncthreads();
    }

    if (t < 128) { ssum[t] = 0.f; ssq[t] = 0.f; }
    __syncthreads();

    #pragma unroll
    for (int j = 0; j < 4; ++j) {
        int nl = wn + j*16 + lm;
        float psum = 0.f, psq = 0.f;
        #pragma unroll
        for (int i = 0; i < 4; ++i) {
            #pragma unroll
            for (int r = 0; r < 4; ++r) {
                int ml = wm + i*16 + quad*4 + r;
                float v = acc[i][j][r];
                C[(long)(m0 + ml) * ldc + n0 + nl] = v;
                psum += v; psq += v * v;
            }
        }
        atomicAdd(&ssum[nl], psum);
        atomicAdd(&ssq[nl], psq);
    }
    __syncthreads();
    if (t < 128) {
        atomicAdd(&gsum[n0 + t], ssum[t]);
        atomicAdd(&gsq[n0 + t],  ssq[t]);
    }
}

__global__ void bn_fin(const float* __restrict__ gsum, const float* __restrict__ gsq,
                       const float* __restrict__ g, const float* __restrict__ b,
                       float* __restrict__ a_out, float* __restrict__ s_out, int nch)
{
    int c = blockIdx.x * blockDim.x + threadIdx.x;
    if (c >= nch) return;
    float inv  = 1.f / (float)MROWS;
    float mean = gsum[c] * inv;
    float var  = gsq[c] * inv - mean * mean;
    float a    = g[c] * rsqrtf(var + EPSV);
    a_out[c] = a;
    s_out[c] = b[c] - mean * a;
}

// ---------------- attention: one block (13 waves, 832 threads) per (batch, head).
// v5: one mt-tile per wave (13 tiles = 13 waves) -> no v4 wave imbalance (5/8 waves
// idle through pass 2). Single-pass softmax restored (no QK recompute): with plain
// __launch_bounds__(832) there is no artificial VGPR cap; LDS (80,384 B) is the sole
// occupancy limiter -> 2 blocks/CU = 26 waves/CU regardless of VGPR<=288.
// ks staging write vectorized to one half8 (rotation keeps 8 elems contiguous).
__global__ __launch_bounds__(832) void attn_kernel(
    const f16* __restrict__ hbuf, const float* __restrict__ a1, const float* __restrict__ s1,
    const f16* __restrict__ bf, f16* __restrict__ obuf)
{
    __shared__ f16   ks[208][32];
    __shared__ f16   vT[128][256];
    __shared__ float af[192], sf[192];

    const int t  = threadIdx.x;
    const int bb = blockIdx.x >> 3;
    const int hh = blockIdx.x & 7;
    const int wid = t >> 6, lane = t & 63, quad = lane >> 4, lm = lane & 15;

    if (t < 192) { af[t] = a1[hh * HPC + t]; sf[t] = s1[hh * HPC + t]; }
    half8 z8 = {};
    for (int i = t; i < 4096; i += 832) *(half8*)&vT[i >> 5][(i & 31) * 8] = z8;
    if (t < 384) ks[196 + (t >> 5)][t & 31] = (f16)0.f;
    __syncthreads();

    // stage k/v (channels 32..191) with BN1 affine, rotation-swizzled placement
    {
        int t8 = t & 7;
        for (int rr = t >> 3; rr < NTOK; rr += 104) {
            const f16* hrow = hbuf + (long)(bb * NTOK + rr) * HIDN + hh * HPC;
            int sr = swz8(rr);
            #pragma unroll
            for (int cc = 0; cc < 3; ++cc) {
                int cb = 32 + (t8 + cc * 8) * 8;   // 32..216 step 8; skip >=192
                if (cb >= 192) continue;
                half8 raw = *(const half8*)(hrow + cb);
                if (cb < 64) {
                    half8 ov;
                    #pragma unroll
                    for (int e = 0; e < 8; ++e)
                        ov[e] = (f16)((float)raw[e] * af[cb + e] + sf[cb + e]);
                    // rotation start (cb-32+sr)&31 is a multiple of 8 -> contiguous, no wrap
                    *(half8*)&ks[rr][(cb - 32 + sr) & 31] = ov;
                } else {
                    #pragma unroll
                    for (int e = 0; e < 8; ++e) {
                        int c = cb - 64 + e;
                        f16 ov = (f16)((float)raw[e] * af[cb + e] + sf[cb + e]);
                        vT[c][(rr + swz8(c)) & 255] = ov;
                    }
                }
            }
        }
    }
    __syncthreads();

    const int mt = wid;                                  // one tile per wave, 13 waves
    const int qrow = mt * 16 + lm;                       // 0..207 (>=196 masked rows)
    const f16* bfh = bf + hh * 208 * 224;

    // ---- q B-frag direct from global + BN1 affine (q = channels 0..31)
    long grow = (long)bb * NTOK + qrow;
    if (grow > (long)(MROWS - 1)) grow = MROWS - 1;      // clamp tail OOB (values masked)
    half8 qraw = *(const half8*)(hbuf + grow * HIDN + hh * HPC + quad * 8);
    half8 qf;
    #pragma unroll
    for (int e = 0; e < 8; ++e)
        qf[e] = (f16)((float)qraw[e] * af[quad * 8 + e] + sf[quad * 8 + e]);

    // ---- S^T = K·Q^T (13 MFMAs). Lane holds q = qrow (col=lm), k = nt*16 + quad*4 + r.
    f4 sreg[13];
    #pragma unroll
    for (int nt = 0; nt < 13; ++nt) {
        int krow = nt * 16 + lm;
        half8 ak = *(const half8*)&ks[krow][(quad * 8 + swz8(krow)) & 31];
        f4 z = {};
        sreg[nt] = __builtin_amdgcn_mfma_f32_16x16x32_f16(ak, qf, z, 0, 0, 0);
    }

    // ---- scale + bias (mask baked into bias pad rows/cols), running max
    const f16* brow = bfh + qrow * 224 + quad * 4;
    float m = -3.0e38f;
    #pragma unroll
    for (int nt = 0; nt < 13; ++nt) {
        half4 b4 = *(const half4*)(brow + nt * 16);
        #pragma unroll
        for (int r = 0; r < 4; ++r) {
            sreg[nt][r] = fmaf(sreg[nt][r], SCALEV, (float)b4[r]);
            m = fmaxf(m, sreg[nt][r]);
        }
    }
    m = fmaxf(m, __shfl_xor(m, 16));
    m = fmaxf(m, __shfl_xor(m, 32));

    // ---- exp + sum; P stays unnormalized (<=1) f16 in regs as PV A-frags
    float s = 0.f;
    half4 ap[13];
    #pragma unroll
    for (int nt = 0; nt < 13; ++nt) {
        float e0 = __expf(sreg[nt][0] - m);
        float e1 = __expf(sreg[nt][1] - m);
        float e2 = __expf(sreg[nt][2] - m);
        float e3 = __expf(sreg[nt][3] - m);
        s += (e0 + e1) + (e2 + e3);
        ap[nt] = half4{ (f16)e0, (f16)e1, (f16)e2, (f16)e3 };
    }
    s += __shfl_xor(s, 16);
    s += __shfl_xor(s, 32);
    float rinv = 1.f / s;

    // redistribute rinv to output layout (row = quad*4+r)
    float rv[4];
    #pragma unroll
    for (int r = 0; r < 4; ++r) rv[r] = __shfl(rinv, quad * 4 + r);

    // ---- O = P·V via 16x16x16 (A-frag = ap, matches register layout exactly)
    #pragma unroll
    for (int ct = 0; ct < 8; ++ct) {
        int c = ct * 16 + lm;
        int sc = swz8(c);
        f4 oa = {};
        #pragma unroll
        for (int nt = 0; nt < 13; ++nt) {
            half4 bv = *(const half4*)&vT[c][(nt * 16 + quad * 4 + sc) & 255];
            oa = __builtin_amdgcn_mfma_f32_16x16x16f16(ap[nt], bv, oa, 0, 0, 0);
        }
        #pragma unroll
        for (int r = 0; r < 4; ++r) {
            int qr = mt * 16 + quad * 4 + r;
            if (qr < 196) {
                float v  = oa[r] * rv[r];
                float hs = v * fminf(fmaxf(v + 3.f, 0.f), 6.f) * (1.f / 6.f);
                obuf[(long)(bb * NTOK + qr) * DHD + hh * 128 + c] = (f16)hs;
            }
        }
    }
}

__global__ __launch_bounds__(256) void bn_apply(
    float* __restrict__ out, const float* __restrict__ a2, const float* __restrict__ s2)
{
    __shared__ float aL[256], sL[256];
    int t = threadIdx.x;
    aL[t] = a2[t]; sL[t] = s2[t];
    __syncthreads();
    long total = (long)MROWS * 256 / 4;
    for (long i = (long)blockIdx.x * 256 + t; i < total; i += (long)gridDim.x * 256) {
        float4 v = *(float4*)&out[i * 4];
        int cb = (int)((i * 4) & 255);
        v.x = v.x * aL[cb + 0] + sL[cb + 0];
        v.y = v.y * aL[cb + 1] + sL[cb + 1];
        v.z = v.z * aL[cb + 2] + sL[cb + 2];
        v.w = v.w * aL[cb + 3] + sL[cb + 3];
        *(float4*)&out[i * 4] = v;
    }
}

extern "C" void kernel_launch(void* const* d_in, const int* in_sizes, int n_in,
                              void* d_out, int out_size, void* d_ws, size_t ws_size,
                              hipStream_t stream)
{
    (void)in_sizes; (void)n_in; (void)out_size; (void)ws_size;
    const float* x          = (const float*)d_in[0];
    const float* Wqkv       = (const float*)d_in[1];
    const float* g1         = (const float*)d_in[2];
    const float* b1         = (const float*)d_in[3];
    const float* bias_table = (const float*)d_in[4];
    const float* Wproj      = (const float*)d_in[5];
    const float* g2         = (const float*)d_in[6];
    const float* b2         = (const float*)d_in[7];
    const int*   idxs       = (const int*)d_in[8];
    float*       out        = (float*)d_out;

    char* ws = (char*)d_ws;
    f16* hbuf = (f16*)ws;                                 // [0, 154,140,672)
    f16* obuf = (f16*)(ws + 154140672LL);                 // [154,140,672, 256,901,120)
    f16* xh   = (f16*)(ws + 154140672LL);                 // overlay (dead before attn)
    f16* wqh  = (f16*)(ws + 154140672LL + 25690112LL);
    f16* wph  = (f16*)ws;                                 // overlay hbuf (dead after attn)
    float* stats = (float*)(ws + 256901120LL);
    float* gsum1 = stats;            float* gsq1 = stats + 1536;
    float* gsum2 = stats + 3072;     float* gsq2 = stats + 3328;
    float* a1 = stats + 3584;        float* s1 = a1 + 1536;
    float* a2 = s1 + 1536;           float* s2 = a2 + 256;
    f16* bias_full = (f16*)(ws + 256901120LL + 65536LL);  // 8*208*224*2 = 745,472 B

    hipMemsetAsync(stats, 0, 3584 * sizeof(float), stream);

    cvt_f32_f16<<<12544, 256, 0, stream>>>(x, xh, 3211264);
    cvt_f32_f16<<<384,   256, 0, stream>>>(Wqkv, wqh, 98304);
    build_bias<<<1456, 256, 0, stream>>>(bias_table, idxs, bias_full);

    gemm1_qkv<<<dim3(392, 12), 256, 0, stream>>>(xh, wqh, hbuf, gsum1, gsq1);
    bn_fin<<<6, 256, 0, stream>>>(gsum1, gsq1, g1, b1, a1, s1, 1536);

    attn_kernel<<<2048, 832, 0, stream>>>(hbuf, a1, s1, bias_full, obuf);

    cvt_f32_f16<<<256, 256, 0, stream>>>(Wproj, wph, 65536);

    gemm2_proj<<<dim3(392, 2), 256, 0, stream>>>(obuf, wph, out, gsum2, gsq2);
    bn_fin<<<1, 256, 0, stream>>>(gsum2, gsq2, g2, b2, a2, s2, 256);

    bn_apply<<<1024, 256, 0, stream>>>(out, a2, s2);
}